// Round 7
// baseline (192.710 us; speedup 1.0000x reference)
//
#include <hip/hip_runtime.h>
#include <hip/hip_bf16.h>

constexpr int Bt    = 131072;
constexpr int OBS   = 194;

// ---- d_ws layout ----
// bytes [0, 57344)     : W1B | WC1B   (layer-1 B-frags, bf16) -> staged to LDS
// bytes [57344, 92160) : W2B | WC2B | WHB (layer-2 + head B-frags) -> read from L2
constexpr int W1B_S  = 0;
constexpr int WC1B_S = 14336;
constexpr int W2B_S  = 28672;
constexpr int WC2B_S = 36864;
constexpr int WHB_S  = 45056;

typedef short bf8   __attribute__((ext_vector_type(8)));
typedef float f32x4 __attribute__((ext_vector_type(4)));
typedef unsigned int u32;

__device__ __forceinline__ short f2bs(float f) {
    union { __hip_bfloat16 h; short s; } u;
    u.h = __float2bfloat16(f);
    return u.s;
}
__device__ __forceinline__ float bs2f(short s) {
    union { short s; __hip_bfloat16 h; } u;
    u.s = s;
    return __bfloat162float(u.h);
}
__device__ __forceinline__ u32 pk2(float a, float b) {
    union { __hip_bfloat162 h; u32 u; } r;
    r.h = __float22bfloat162_rn(float2{a, b});
    return r.u;
}
__device__ __forceinline__ float fast_tanh(float v) {
    v = fminf(fmaxf(v, -15.f), 15.f);
    float e = __expf(2.f * v);
    return (e - 1.f) * __builtin_amdgcn_rcpf(e + 1.f);
}
// g: per-lane global address. s: WAVE-UNIFORM LDS base — HW writes lane i at s + i*16.
__device__ __forceinline__ void dma16(const void* g, void* s) {
    __builtin_amdgcn_global_load_lds(
        (const __attribute__((address_space(1))) u32*)g,
        (__attribute__((address_space(3))) u32*)s, 16, 0, 0);
}

// ---------------- prep: weights -> B-fragment layout in d_ws (unchanged) ----------------
__global__ void __launch_bounds__(256) prep(
    const float* __restrict__ W1, const float* __restrict__ b1,
    const float* __restrict__ W2, const float* __restrict__ Wh,
    const float* __restrict__ Wc1, const float* __restrict__ bc1,
    const float* __restrict__ Wc2, const float* __restrict__ Wc3,
    short* __restrict__ ws)
{
    const int gid = blockIdx.x * 256 + threadIdx.x;
    const int gsz = gridDim.x * 256;

    for (int i = gid; i < 14336; i += gsz) {
        int j = i & 7, l = (i >> 3) & 63, nt = (i >> 9) & 3, kb = i >> 11;
        int k = kb * 32 + ((l >> 4) << 3) + j;
        int n = nt * 16 + (l & 15);
        short v1 = 0, v2 = 0;
        if (k < OBS) {
            v1 = f2bs(W1[k * 64 + n]);
            v2 = f2bs(Wc1[k * 64 + n]);
        } else if (k == OBS) {              // bias row (A supplies 1.0)
            v1 = f2bs(b1[n]);
            v2 = f2bs(bc1[n]);
        }
        ws[W1B_S + i]  = v1;
        ws[WC1B_S + i] = v2;
    }
    for (int i = gid; i < 8192; i += gsz) {
        int j = i & 7, l = (i >> 3) & 63, nt = (i >> 9) & 3, kb = i >> 11;
        int s = kb * 32 + ((l >> 4) << 3) + j;
        int kp = (s & 3) * 16 + (s >> 2);   // gamma(s)
        int n = nt * 16 + (l & 15);
        ws[W2B_S + i]  = f2bs(W2[kp * 64 + n]);
        ws[WC2B_S + i] = f2bs(Wc2[kp * 64 + n]);
    }
    for (int i = gid; i < 1024; i += gsz) {
        int j = i & 7, l = (i >> 3) & 63, kb = i >> 9;
        int s = kb * 32 + ((l >> 4) << 3) + j;
        int kp = (s & 3) * 16 + (s >> 2);
        int cc = l & 15;
        float v;
        if (cc == 15) v = Wc3[kp];
        else { int e = cc / 5, a = cc - 5 * e; v = Wh[(e * 64 + kp) * 5 + a]; }
        ws[WHB_S + i] = f2bs(v);
    }
}

// ---------------- fused: trunk + head + epilogue, 2 tiles per wave, pipelined ----------------
// 512 blocks x 8 waves x 2 tiles = 8192 tiles; 2 blocks/CU (LDS 75776 B), all resident.
// Per-wave: pack(A) | sync | issue B1 | L1(A) | packB1+issue B2 | backhalf(A) |
// packB2 | L1(B) | backhalf(B).  Split B-burst keeps peak VGPR < 128.
constexpr int FB_LDS = 57344 + 8 * 2304;   // 75776

__global__ void __launch_bounds__(512, 2) fused_ac(
    const float* __restrict__ x, const int* __restrict__ act_in,
    const float* __restrict__ b2, const float* __restrict__ bc2,
    const float* __restrict__ bh, const float* __restrict__ bc3,
    const short* __restrict__ ws,
    float* __restrict__ out)
{
    __shared__ __align__(16) char smem[FB_LDS];
    const int t = threadIdx.x;
    const int l = t & 63, q = (t >> 4) & 3, c = t & 15;
    const int wu = __builtin_amdgcn_readfirstlane(t >> 6);   // wave id, SGPR

    // layer-1 weights -> LDS: 56 x 1024-B chunks, 7 per wave, uniform dest
    #pragma unroll
    for (int i = 0; i < 7; ++i) {
        int ch = wu * 7 + i;
        dma16((const char*)ws + ch * 1024 + l * 16, smem + ch * 1024);
    }

    const bf8* fW1L  = reinterpret_cast<const bf8*>(smem);
    const bf8* fWc1L = reinterpret_cast<const bf8*>(smem + 28672);
    short* bb = reinterpret_cast<short*>(smem + 57344 + wu * 2304);  // per-wave bounce

    const int tA = blockIdx.x * 16 + wu * 2;
    const int tB = tA + 1;
    const float* xrA = x + (size_t)tA * 16 * OBS + (size_t)c * OBS;
    const float* xrB = x + (size_t)tB * 16 * OBS + (size_t)c * OBS;

    // ---- per-lane biases ----
    float b2v[4], bc2v[4];
    #pragma unroll
    for (int nt = 0; nt < 4; ++nt) {
        b2v[nt]  = b2[nt * 16 + c];
        bc2v[nt] = bc2[nt * 16 + c];
    }
    float bhv = (c < 15) ? bh[c] : bc3[0];

    // ---- tile A: load + pack inline ----
    union AF { u32 u[4]; bf8 v; } afA[7], afB[7];
    float4 f40A;
    #pragma unroll
    for (int kb = 0; kb < 6; ++kb) {
        float4 a = *reinterpret_cast<const float4*>(xrA + kb * 32 + q * 8);
        float4 b = *reinterpret_cast<const float4*>(xrA + kb * 32 + q * 8 + 4);
        if (kb == 0) f40A = a;
        afA[kb].u[0] = pk2(a.x, a.y);
        afA[kb].u[1] = pk2(a.z, a.w);
        afA[kb].u[2] = pk2(b.x, b.y);
        afA[kb].u[3] = pk2(b.z, b.w);
    }
    afA[6].u[0] = 0; afA[6].u[1] = 0; afA[6].u[2] = 0; afA[6].u[3] = 0;
    if (q == 0) {
        float2 v = *reinterpret_cast<const float2*>(xrA + 192);
        afA[6].u[0] = pk2(v.x, v.y);
        afA[6].u[1] = pk2(1.0f, 0.0f);
    }
    int actA = 0, evA = 0, actB = 0, evB = 0;
    if (l < 16) {
        actA = act_in[tA * 16 + l];
        actB = act_in[tB * 16 + l];
        float bsa = f40A.x;
        if (f40A.y > bsa) { bsa = f40A.y; evA = 1; }
        if (f40A.z > bsa) evA = 2;
    }

    // ---- shared accumulators + phase lambdas ----
    f32x4 aa[4], ac[4];

    auto layer1 = [&](union AF* af) {
        #pragma unroll
        for (int nt = 0; nt < 4; ++nt) {
            aa[nt] = f32x4{0.f, 0.f, 0.f, 0.f};
            ac[nt] = f32x4{0.f, 0.f, 0.f, 0.f};
        }
        #pragma unroll
        for (int kb = 0; kb < 7; ++kb) {
            bf8 a = af[kb].v;
            #pragma unroll
            for (int nt = 0; nt < 4; ++nt) {
                aa[nt] = __builtin_amdgcn_mfma_f32_16x16x32_bf16(a, fW1L [(kb * 4 + nt) * 64 + l], aa[nt], 0, 0, 0);
                ac[nt] = __builtin_amdgcn_mfma_f32_16x16x32_bf16(a, fWc1L[(kb * 4 + nt) * 64 + l], ac[nt], 0, 0, 0);
            }
        }
    };

    auto bounce = [&](f32x4* cc4, bf8* fr) {
        #pragma unroll
        for (int r = 0; r < 4; ++r) {
            uint2 p;
            p.x = pk2(fast_tanh(cc4[0][r]), fast_tanh(cc4[1][r]));
            p.y = pk2(fast_tanh(cc4[2][r]), fast_tanh(cc4[3][r]));
            *reinterpret_cast<uint2*>(&bb[(q * 4 + r) * 72 + 4 * c]) = p;
        }
        #pragma unroll
        for (int kb = 0; kb < 2; ++kb)
            fr[kb] = *reinterpret_cast<const bf8*>(&bb[c * 72 + kb * 32 + q * 8]);
    };

    const bf8* fW2G  = reinterpret_cast<const bf8*>((const char*)ws + 57344);
    const bf8* fWc2G = reinterpret_cast<const bf8*>((const char*)ws + 73728);
    const bf8* fWhG  = reinterpret_cast<const bf8*>((const char*)ws + 90112);

    auto backhalf = [&](int act, int evc, int tt) {
        bf8 xa[2], xc[2];
        bounce(aa, xa);
        bounce(ac, xc);
        #pragma unroll
        for (int nt = 0; nt < 4; ++nt) {
            aa[nt] = f32x4{b2v[nt], b2v[nt], b2v[nt], b2v[nt]};
            ac[nt] = f32x4{bc2v[nt], bc2v[nt], bc2v[nt], bc2v[nt]};
        }
        #pragma unroll
        for (int kb = 0; kb < 2; ++kb) {
            #pragma unroll
            for (int nt = 0; nt < 4; ++nt) {
                aa[nt] = __builtin_amdgcn_mfma_f32_16x16x32_bf16(xa[kb], fW2G [(kb * 4 + nt) * 64 + l], aa[nt], 0, 0, 0);
                ac[nt] = __builtin_amdgcn_mfma_f32_16x16x32_bf16(xc[kb], fWc2G[(kb * 4 + nt) * 64 + l], ac[nt], 0, 0, 0);
            }
        }
        bf8 fa[2], fc[2];
        bounce(aa, fa);
        bounce(ac, fc);
        f32x4 lg = f32x4{bhv, bhv, bhv, bhv};
        f32x4 vv = f32x4{bhv, bhv, bhv, bhv};
        #pragma unroll
        for (int kb = 0; kb < 2; ++kb) {
            bf8 bw = fWhG[kb * 64 + l];
            lg = __builtin_amdgcn_mfma_f32_16x16x32_bf16(fa[kb], bw, lg, 0, 0, 0);
            vv = __builtin_amdgcn_mfma_f32_16x16x32_bf16(fc[kb], bw, vv, 0, 0, 0);
        }
        short* lw = bb;
        float* vb = reinterpret_cast<float*>(bb + 1120);
        #pragma unroll
        for (int r = 0; r < 4; ++r)
            lw[(q * 4 + r) * 18 + c] = f2bs(lg[r]);
        if (c == 15) {
            #pragma unroll
            for (int r = 0; r < 4; ++r)
                vb[q * 4 + r] = vv[r];
        }
        if (l < 16) {
            float lgv[5];
            #pragma unroll
            for (int a = 0; a < 5; ++a)
                lgv[a] = bs2f(lw[c * 18 + evc * 5 + a]);
            float mx = lgv[0];
            #pragma unroll
            for (int a = 1; a < 5; ++a) mx = fmaxf(mx, lgv[a]);
            float se = 0.f;
            #pragma unroll
            for (int a = 0; a < 5; ++a) se += __expf(lgv[a] - mx);
            float lse = __logf(se) + mx;
            float lsel = lgv[0];
            #pragma unroll
            for (int a = 1; a < 5; ++a) lsel = (act == a) ? lgv[a] : lsel;
            float ent = 0.f;
            #pragma unroll
            for (int a = 0; a < 5; ++a) { float lp = lgv[a] - lse; ent -= __expf(lp) * lp; }
            const int gm = tt * 16 + c;
            out[gm]          = (float)act;
            out[Bt + gm]     = lsel - lse;
            out[2 * Bt + gm] = ent;
            out[3 * Bt + gm] = vb[c];
        }
    };

    __syncthreads();   // weights resident

    // ---- issue B burst 1 (kb 0-2) ----
    float4 rB0[6];
    #pragma unroll
    for (int kb = 0; kb < 3; ++kb) {
        rB0[2 * kb]     = *reinterpret_cast<const float4*>(xrB + kb * 32 + q * 8);
        rB0[2 * kb + 1] = *reinterpret_cast<const float4*>(xrB + kb * 32 + q * 8 + 4);
    }
    __builtin_amdgcn_sched_barrier(0);

    // ---- layer 1 (A)  [covers burst 1] ----
    layer1(afA);

    // ---- pack B1 + evB; issue B burst 2 (kb 3-5 + tail) ----
    #pragma unroll
    for (int kb = 0; kb < 3; ++kb) {
        float4 a = rB0[2 * kb], b = rB0[2 * kb + 1];
        afB[kb].u[0] = pk2(a.x, a.y);
        afB[kb].u[1] = pk2(a.z, a.w);
        afB[kb].u[2] = pk2(b.x, b.y);
        afB[kb].u[3] = pk2(b.z, b.w);
    }
    if (l < 16) {
        float4 f40B = rB0[0];
        float bsb = f40B.x;
        if (f40B.y > bsb) { bsb = f40B.y; evB = 1; }
        if (f40B.z > bsb) evB = 2;
    }
    float4 rB1[6];
    float2 t6B = float2{0.f, 0.f};
    #pragma unroll
    for (int kb = 3; kb < 6; ++kb) {
        rB1[2 * (kb - 3)]     = *reinterpret_cast<const float4*>(xrB + kb * 32 + q * 8);
        rB1[2 * (kb - 3) + 1] = *reinterpret_cast<const float4*>(xrB + kb * 32 + q * 8 + 4);
    }
    if (q == 0) t6B = *reinterpret_cast<const float2*>(xrB + 192);
    __builtin_amdgcn_sched_barrier(0);

    // ---- backhalf (A)  [covers burst 2] ----
    backhalf(actA, evA, tA);

    // ---- pack B2 ----
    #pragma unroll
    for (int kb = 3; kb < 6; ++kb) {
        float4 a = rB1[2 * (kb - 3)], b = rB1[2 * (kb - 3) + 1];
        afB[kb].u[0] = pk2(a.x, a.y);
        afB[kb].u[1] = pk2(a.z, a.w);
        afB[kb].u[2] = pk2(b.x, b.y);
        afB[kb].u[3] = pk2(b.z, b.w);
    }
    afB[6].u[0] = 0; afB[6].u[1] = 0; afB[6].u[2] = 0; afB[6].u[3] = 0;
    if (q == 0) {
        afB[6].u[0] = pk2(t6B.x, t6B.y);
        afB[6].u[1] = pk2(1.0f, 0.0f);
    }

    // ---- layer 1 (B) + backhalf (B) ----
    layer1(afB);
    backhalf(actB, evB, tB);
}

extern "C" void kernel_launch(void* const* d_in, const int* in_sizes, int n_in,
                              void* d_out, int out_size, void* d_ws, size_t ws_size,
                              hipStream_t stream) {
    const float* x   = (const float*)d_in[0];
    const int*   act = (const int*)  d_in[1];
    const float* W1  = (const float*)d_in[2];
    const float* b1  = (const float*)d_in[3];
    const float* W2  = (const float*)d_in[4];
    const float* b2  = (const float*)d_in[5];
    const float* Wh  = (const float*)d_in[6];
    const float* bh  = (const float*)d_in[7];
    const float* Wc1 = (const float*)d_in[8];
    const float* bc1 = (const float*)d_in[9];
    const float* Wc2 = (const float*)d_in[10];
    const float* bc2 = (const float*)d_in[11];
    const float* Wc3 = (const float*)d_in[12];
    const float* bc3 = (const float*)d_in[13];
    float* out = (float*)d_out;
    short* ws  = (short*)d_ws;

    hipLaunchKernelGGL(prep, dim3(32), dim3(256), 0, stream,
                       W1, b1, W2, Wh, Wc1, bc1, Wc2, Wc3, ws);
    hipLaunchKernelGGL(fused_ac, dim3(512), dim3(512), 0, stream,
                       x, act, b2, bc2, bh, bc3, ws, out);
}

// Round 8
// 192.073 us; speedup vs baseline: 1.0033x; 1.0033x over previous
//
#include <hip/hip_runtime.h>
#include <hip/hip_bf16.h>

constexpr int Bt    = 131072;
constexpr int OBS   = 194;

// ---- d_ws layout ----
// bytes [0, 57344)     : W1B | WC1B   (layer-1 B-frags, bf16)  -> read from L1/L2
// bytes [57344, 92160) : W2B | WC2B | WHB (layer-2 + head B-frags) -> read from L1/L2
constexpr int W1B_S  = 0;
constexpr int WC1B_S = 14336;
constexpr int W2B_S  = 28672;
constexpr int WC2B_S = 36864;
constexpr int WHB_S  = 45056;

typedef short bf8   __attribute__((ext_vector_type(8)));
typedef float f32x4 __attribute__((ext_vector_type(4)));
typedef unsigned int u32;

__device__ __forceinline__ short f2bs(float f) {
    union { __hip_bfloat16 h; short s; } u;
    u.h = __float2bfloat16(f);
    return u.s;
}
__device__ __forceinline__ float bs2f(short s) {
    union { short s; __hip_bfloat16 h; } u;
    u.s = s;
    return __bfloat162float(u.h);
}
__device__ __forceinline__ u32 pk2(float a, float b) {
    union { __hip_bfloat162 h; u32 u; } r;
    r.h = __float22bfloat162_rn(float2{a, b});
    return r.u;
}
__device__ __forceinline__ float fast_tanh(float v) {
    v = fminf(fmaxf(v, -15.f), 15.f);
    float e = __expf(2.f * v);
    return (e - 1.f) * __builtin_amdgcn_rcpf(e + 1.f);
}

// ---------------- prep: weights -> B-fragment layout in d_ws (unchanged) ----------------
__global__ void __launch_bounds__(256) prep(
    const float* __restrict__ W1, const float* __restrict__ b1,
    const float* __restrict__ W2, const float* __restrict__ Wh,
    const float* __restrict__ Wc1, const float* __restrict__ bc1,
    const float* __restrict__ Wc2, const float* __restrict__ Wc3,
    short* __restrict__ ws)
{
    const int gid = blockIdx.x * 256 + threadIdx.x;
    const int gsz = gridDim.x * 256;

    for (int i = gid; i < 14336; i += gsz) {
        int j = i & 7, l = (i >> 3) & 63, nt = (i >> 9) & 3, kb = i >> 11;
        int k = kb * 32 + ((l >> 4) << 3) + j;
        int n = nt * 16 + (l & 15);
        short v1 = 0, v2 = 0;
        if (k < OBS) {
            v1 = f2bs(W1[k * 64 + n]);
            v2 = f2bs(Wc1[k * 64 + n]);
        } else if (k == OBS) {              // bias row (A supplies 1.0)
            v1 = f2bs(b1[n]);
            v2 = f2bs(bc1[n]);
        }
        ws[W1B_S + i]  = v1;
        ws[WC1B_S + i] = v2;
    }
    for (int i = gid; i < 8192; i += gsz) {
        int j = i & 7, l = (i >> 3) & 63, nt = (i >> 9) & 3, kb = i >> 11;
        int s = kb * 32 + ((l >> 4) << 3) + j;
        int kp = (s & 3) * 16 + (s >> 2);   // gamma(s)
        int n = nt * 16 + (l & 15);
        ws[W2B_S + i]  = f2bs(W2[kp * 64 + n]);
        ws[WC2B_S + i] = f2bs(Wc2[kp * 64 + n]);
    }
    for (int i = gid; i < 1024; i += gsz) {
        int j = i & 7, l = (i >> 3) & 63, kb = i >> 9;
        int s = kb * 32 + ((l >> 4) << 3) + j;
        int kp = (s & 3) * 16 + (s >> 2);
        int cc = l & 15;
        float v;
        if (cc == 15) v = Wc3[kp];
        else { int e = cc / 5, a = cc - 5 * e; v = Wh[(e * 64 + kp) * 5 + a]; }
        ws[WHB_S + i] = f2bs(v);
    }
}

// ---------------- fused: one wave per 16-row tile, barrier-free ----------------
// x ingest is LINEAR (lane l reads tile+i*1024+l*16: 8 fully-used 128-B lines per
// instruction, 1x transaction amplification) -> regs -> wave-local LDS ->
// fragment-order ds_read_b64 + pack.  The LDS region is wave-private, so the
// load->write->read->reuse chain needs NO barriers (in-order DS pipe).
// All weight B-frags stream from global (L1/L2-hot, 1-KB coalesced per instr).
// 2048 blocks x 256 thr (4 waves): LDS 50176 B -> 3 blocks/CU, 12 waves/CU.
constexpr int XT_STR = 12544;              // per-wave stage stride (12416 + pad)
constexpr int FB_LDS = 4 * XT_STR;         // 50176

__global__ void __launch_bounds__(256, 3) fused_ac(
    const float* __restrict__ x, const int* __restrict__ act_in,
    const float* __restrict__ b2, const float* __restrict__ bc2,
    const float* __restrict__ bh, const float* __restrict__ bc3,
    const short* __restrict__ ws,
    float* __restrict__ out)
{
    __shared__ __align__(16) char smem[FB_LDS];
    const int t = threadIdx.x;
    const int l = t & 63, q = (t >> 4) & 3, c = t & 15;
    const int wu = __builtin_amdgcn_readfirstlane(t >> 6);   // wave id, SGPR

    const int tt = blockIdx.x * 4 + wu;          // 2048 blocks x 4 waves = 8192 tiles
    const char* src = (const char*)x + (size_t)tt * 12416;
    char* xs = smem + wu * XT_STR;               // wave-private stage

    // ---- 1) linear coalesced load to regs (13 x dwordx4, all in flight) ----
    int4 stage[13];
    #pragma unroll
    for (int i = 0; i < 12; ++i)
        stage[i] = *reinterpret_cast<const int4*>(src + i * 1024 + l * 16);
    stage[12] = *reinterpret_cast<const int4*>(src + 11392 + l * 16);  // tail (overlaps ch11, same data)

    // ---- 2) linear ds_write (compiler interleaves counted vmcnt with these) ----
    #pragma unroll
    for (int i = 0; i < 12; ++i)
        *reinterpret_cast<int4*>(xs + i * 1024 + l * 16) = stage[i];
    *reinterpret_cast<int4*>(xs + 11392 + l * 16) = stage[12];

    // ---- 3) fragment-order reads + pack: lane (q,c) holds A[row=c][kb*32+q*8..+8) ----
    union AF { u32 u[4]; bf8 v; } af[7];
    #pragma unroll
    for (int kb = 0; kb < 6; ++kb) {
        #pragma unroll
        for (int j = 0; j < 4; ++j) {
            float2 v = *reinterpret_cast<const float2*>(xs + c * 776 + kb * 128 + q * 32 + j * 8);
            af[kb].u[j] = pk2(v.x, v.y);
        }
    }
    af[6].u[0] = 0; af[6].u[1] = 0; af[6].u[2] = 0; af[6].u[3] = 0;
    if (q == 0) {                       // k=192,193 data; k=194 -> 1.0 (bias row)
        float2 v = *reinterpret_cast<const float2*>(xs + c * 776 + 768);
        af[6].u[0] = pk2(v.x, v.y);
        af[6].u[1] = pk2(1.0f, 0.0f);
    }

    // ---- ev = argmax(x[0..2]) + action, in the lane that owns the row (l<16) ----
    int act = 0, evc = 0;
    if (l < 16) {
        act = act_in[tt * 16 + l];
        float2 v01 = *reinterpret_cast<const float2*>(xs + l * 776);
        float  v2  = *reinterpret_cast<const float*>(xs + l * 776 + 8);
        float b = v01.x;
        if (v01.y > b) { b = v01.y; evc = 1; }
        if (v2 > b) evc = 2;
    }

    // ---- per-lane biases (tiny, L1-hot across all waves) ----
    float b2v[4], bc2v[4];
    #pragma unroll
    for (int nt = 0; nt < 4; ++nt) {
        b2v[nt]  = b2[nt * 16 + c];
        bc2v[nt] = bc2[nt * 16 + c];
    }
    float bhv = (c < 15) ? bh[c] : bc3[0];

    // ---- weight fragment pointers (global; 1-KB coalesced per instruction) ----
    const bf8* fW1G  = reinterpret_cast<const bf8*>((const char*)ws);
    const bf8* fWc1G = reinterpret_cast<const bf8*>((const char*)ws + 28672);
    const bf8* fW2G  = reinterpret_cast<const bf8*>((const char*)ws + 57344);
    const bf8* fWc2G = reinterpret_cast<const bf8*>((const char*)ws + 73728);
    const bf8* fWhG  = reinterpret_cast<const bf8*>((const char*)ws + 90112);

    // ---- layer 1: actor + critic (bias folded via k=194 row) ----
    f32x4 aa[4], ac[4];
    #pragma unroll
    for (int nt = 0; nt < 4; ++nt) {
        aa[nt] = f32x4{0.f, 0.f, 0.f, 0.f};
        ac[nt] = f32x4{0.f, 0.f, 0.f, 0.f};
    }
    #pragma unroll
    for (int kb = 0; kb < 7; ++kb) {
        bf8 a = af[kb].v;
        #pragma unroll
        for (int nt = 0; nt < 4; ++nt) {
            aa[nt] = __builtin_amdgcn_mfma_f32_16x16x32_bf16(a, fW1G [(kb * 4 + nt) * 64 + l], aa[nt], 0, 0, 0);
            ac[nt] = __builtin_amdgcn_mfma_f32_16x16x32_bf16(a, fWc1G[(kb * 4 + nt) * 64 + l], ac[nt], 0, 0, 0);
        }
    }

    // ---- bounce helper: reuses the (now dead) x-stage as wave-private scratch ----
    short* bb = reinterpret_cast<short*>(xs);
    auto bounce = [&](f32x4* cc4, bf8* fr) {
        #pragma unroll
        for (int r = 0; r < 4; ++r) {
            uint2 p;
            p.x = pk2(fast_tanh(cc4[0][r]), fast_tanh(cc4[1][r]));
            p.y = pk2(fast_tanh(cc4[2][r]), fast_tanh(cc4[3][r]));
            *reinterpret_cast<uint2*>(&bb[(q * 4 + r) * 72 + 4 * c]) = p;
        }
        #pragma unroll
        for (int kb = 0; kb < 2; ++kb)
            fr[kb] = *reinterpret_cast<const bf8*>(&bb[c * 72 + kb * 32 + q * 8]);
    };

    // ---- transpose h (actor, then critic) ----
    bf8 xa[2], xc[2];
    bounce(aa, xa);
    bounce(ac, xc);

    // ---- layer 2 (bias via acc init) ----
    #pragma unroll
    for (int nt = 0; nt < 4; ++nt) {
        aa[nt] = f32x4{b2v[nt], b2v[nt], b2v[nt], b2v[nt]};
        ac[nt] = f32x4{bc2v[nt], bc2v[nt], bc2v[nt], bc2v[nt]};
    }
    #pragma unroll
    for (int kb = 0; kb < 2; ++kb) {
        #pragma unroll
        for (int nt = 0; nt < 4; ++nt) {
            aa[nt] = __builtin_amdgcn_mfma_f32_16x16x32_bf16(xa[kb], fW2G [(kb * 4 + nt) * 64 + l], aa[nt], 0, 0, 0);
            ac[nt] = __builtin_amdgcn_mfma_f32_16x16x32_bf16(xc[kb], fWc2G[(kb * 4 + nt) * 64 + l], ac[nt], 0, 0, 0);
        }
    }

    // ---- transpose feat (actor, then critic) ----
    bf8 fa[2], fc[2];
    bounce(aa, fa);
    bounce(ac, fc);

    // ---- head: feat[16x64] @ [64x16] (cols 0-14 logits, col 15 value) ----
    f32x4 lg = f32x4{bhv, bhv, bhv, bhv};
    f32x4 vv = f32x4{bhv, bhv, bhv, bhv};
    #pragma unroll
    for (int kb = 0; kb < 2; ++kb) {
        bf8 bw = fWhG[kb * 64 + l];
        lg = __builtin_amdgcn_mfma_f32_16x16x32_bf16(fa[kb], bw, lg, 0, 0, 0);
        vv = __builtin_amdgcn_mfma_f32_16x16x32_bf16(fc[kb], bw, vv, 0, 0, 0);
    }

    // ---- logits|value -> wave-private scratch ----
    short* lw = bb;
    float* vb = reinterpret_cast<float*>(bb + 1120);
    #pragma unroll
    for (int r = 0; r < 4; ++r)
        lw[(q * 4 + r) * 18 + c] = f2bs(lg[r]);
    if (c == 15) {
        #pragma unroll
        for (int r = 0; r < 4; ++r)
            vb[q * 4 + r] = vv[r];
    }

    // ---- epilogue: lanes 0-15 (row c==l), all inputs wave-local ----
    if (l < 16) {
        float lgv[5];
        #pragma unroll
        for (int a = 0; a < 5; ++a)
            lgv[a] = bs2f(lw[c * 18 + evc * 5 + a]);
        float mx = lgv[0];
        #pragma unroll
        for (int a = 1; a < 5; ++a) mx = fmaxf(mx, lgv[a]);
        float se = 0.f;
        #pragma unroll
        for (int a = 0; a < 5; ++a) se += __expf(lgv[a] - mx);
        float lse = __logf(se) + mx;
        float lsel = lgv[0];
        #pragma unroll
        for (int a = 1; a < 5; ++a) lsel = (act == a) ? lgv[a] : lsel;
        float ent = 0.f;
        #pragma unroll
        for (int a = 0; a < 5; ++a) { float lp = lgv[a] - lse; ent -= __expf(lp) * lp; }

        const int gm = tt * 16 + c;
        out[gm]          = (float)act;
        out[Bt + gm]     = lsel - lse;
        out[2 * Bt + gm] = ent;
        out[3 * Bt + gm] = vb[c];
    }
}

extern "C" void kernel_launch(void* const* d_in, const int* in_sizes, int n_in,
                              void* d_out, int out_size, void* d_ws, size_t ws_size,
                              hipStream_t stream) {
    const float* x   = (const float*)d_in[0];
    const int*   act = (const int*)  d_in[1];
    const float* W1  = (const float*)d_in[2];
    const float* b1  = (const float*)d_in[3];
    const float* W2  = (const float*)d_in[4];
    const float* b2  = (const float*)d_in[5];
    const float* Wh  = (const float*)d_in[6];
    const float* bh  = (const float*)d_in[7];
    const float* Wc1 = (const float*)d_in[8];
    const float* bc1 = (const float*)d_in[9];
    const float* Wc2 = (const float*)d_in[10];
    const float* bc2 = (const float*)d_in[11];
    const float* Wc3 = (const float*)d_in[12];
    const float* bc3 = (const float*)d_in[13];
    float* out = (float*)d_out;
    short* ws  = (short*)d_ws;

    hipLaunchKernelGGL(prep, dim3(32), dim3(256), 0, stream,
                       W1, b1, W2, Wh, Wc1, bc1, Wc2, Wc3, ws);
    hipLaunchKernelGGL(fused_ac, dim3(2048), dim3(256), 0, stream,
                       x, act, b2, bc2, bh, bc3, ws, out);
}